// Round 2
// baseline (210.892 us; speedup 1.0000x reference)
//
#include <hip/hip_runtime.h>
#include <hip/hip_bf16.h>

#define TGT 256
#define BSZ 8
#define E   256
#define SRC 4096

typedef __attribute__((ext_vector_type(8))) short           bf16x8;
typedef __attribute__((ext_vector_type(4))) float           f32x4;
typedef __attribute__((ext_vector_type(4))) float           f4;
typedef __attribute__((ext_vector_type(8))) unsigned short  u16x8;
typedef __attribute__((ext_vector_type(4))) unsigned short  u16x4;

__device__ inline unsigned short f2b(float x) {
    union { __hip_bfloat16 h; unsigned short u; } cv;
    cv.h = __float2bfloat16(x);
    return cv.u;
}

__device__ inline bf16x8 cvt8v(const float* __restrict__ p) {
    f4 lo = *(const f4*)p;
    f4 hi = *(const f4*)(p + 4);
    bf16x8 r;
    #pragma unroll
    for (int j = 0; j < 4; ++j) { r[j] = (short)f2b(lo[j]); r[4 + j] = (short)f2b(hi[j]); }
    return r;
}

// ---------------------------------------------------------------------------
// prep_vw: grid (64, 9).
//  by<8 : VW pass — for b=by, s-chunk of 64 rows:
//           VW[s, n] = sum_e V[s,b,e] * W[n,e]   (bf16 MFMA, fp32 acc)
//         then store VW in gemm1's B-fragment order (bf16):
//           vwf[(((b*16+et)*128 + ks)*64 + lane)*8 + j] = VW[k][n],
//           n = et*16 + (lane&15), k = ks*32 + (lane>>4)*8 + j.
//         W-frags are built on the fly from global W (L2-resident, 256 KB).
//  by==8: out0 init — out0[t,b,e] = bias[e]  (gemm1 atomically accumulates;
//         runs every launch -> idempotent).
// Projection moved here via linearity: (mask@V)@W^T == mask@(V@W^T).
// ---------------------------------------------------------------------------
__global__ __launch_bounds__(256) void prep_vw(
    const float* __restrict__ value, const float* __restrict__ wgt,
    const float* __restrict__ bias,
    unsigned short* __restrict__ vwf, float* __restrict__ out0)
{
    const int tid = threadIdx.x;

    if (blockIdx.y == 8) {               // ---- bias-init of out0 (2 MB)
        #pragma unroll
        for (int s = 0; s < 8; ++s) {
            int f4i = s * 16384 + blockIdx.x * 256 + tid;   // 0..131071
            *(f4*)(out0 + (size_t)f4i * 4) = *(const f4*)(bias + (f4i & 63) * 4);
        }
        return;
    }

    __shared__ unsigned short tile[64 * 264];   // pitch 264 u16 (528B, 8B-aligned rows)
    const int sc64 = blockIdx.x;                // 0..63 (s-chunk)
    const int b    = blockIdx.y;
    const int s0   = sc64 * 64;

    // ---- stage V chunk (64 s-rows x 256 e) -> bf16 LDS
    #pragma unroll
    for (int i = 0; i < 16; ++i) {
        int lin = i * 256 + tid;                // 0..4095
        int row = lin >> 6;                     // s-local 0..63
        int c4  = lin & 63;                     // e float4 idx
        f4 v = *(const f4*)(value + (size_t)(s0 + row) * (BSZ * E)
                                  + (size_t)b * E + c4 * 4);
        u16x4 pk;
        #pragma unroll
        for (int j = 0; j < 4; ++j) pk[j] = f2b(v[j]);
        *(u16x4*)&tile[row * 264 + c4 * 4] = pk;
    }
    __syncthreads();

    const int w    = tid >> 6;                  // wave 0..3 owns s-rows [w*16, w*16+16)
    const int lane = tid & 63;
    const int quad = lane >> 4;
    const int l15  = lane & 15;

    // A-frags: m = s-local (w*16 + l15), k = e
    bf16x8 a[8];
    #pragma unroll
    for (int ks = 0; ks < 8; ++ks)
        a[ks] = *(const bf16x8*)&tile[(w * 16 + l15) * 264 + ks * 32 + quad * 8];

    // ---- VW = Vtile @ W^T ; D tiles overwrite this wave's own rows of `tile`
    // (A-frags already in registers; each wave reads/writes only its 16 rows)
    const float* wrow = wgt + (size_t)l15 * E + quad * 8;   // + et*16*E + ks*32
    #pragma unroll
    for (int et = 0; et < 16; ++et) {
        f32x4 acc = {};
        #pragma unroll
        for (int ks = 0; ks < 8; ++ks) {
            bf16x8 bb = cvt8v(wrow + (size_t)(et * 16) * E + ks * 32);
            acc = __builtin_amdgcn_mfma_f32_16x16x32_bf16(a[ks], bb, acc, 0, 0, 0);
        }
        // D layout: col = lane&15 (n-local), row = quad*4 + r (m-local)
        #pragma unroll
        for (int r = 0; r < 4; ++r)
            tile[(w * 16 + quad * 4 + r) * 264 + et * 16 + l15] = f2b(acc[r]);
    }
    __syncthreads();

    // ---- repack VW tile (rows = s-local, cols = n) into B-frag order
    #pragma unroll
    for (int i = 0; i < 8; ++i) {
        int o    = i * 256 + tid;               // 0..2047 octets
        int et   = o >> 7;
        int ksl  = (o >> 6) & 1;
        int ln   = o & 63;
        int q2   = ln >> 4, p15 = ln & 15;
        u16x8 pk;
        #pragma unroll
        for (int j = 0; j < 8; ++j)
            pk[j] = tile[(ksl * 32 + q2 * 8 + j) * 264 + et * 16 + p15];
        size_t ks = (size_t)sc64 * 2 + ksl;
        *(u16x8*)&vwf[((((size_t)b * 16 + et) * 128 + ks) * 64 + ln) * 8] = pk;
    }
}

// ---------------------------------------------------------------------------
// gemm1: per block (b, tt, kc):
//   acc = M_b[t-tile, kc-chunk] @ VW_b[kc-chunk]   (+ fused out1 copy)
//   atomicAdd acc into out0 (bias pre-seeded; fp32, no re-rounding).
// Accs are direct out0 contributions now (projection folded into VW), so the
// entire ct/proj epilogue of the previous version is gone.
// Block = (b, tt, kc): 8*8*8 = 512 blocks (2/CU), 512 thr.
// ---------------------------------------------------------------------------
#define AP 136   // A pitch u16: 272 B rows (8B-aligned)

__global__ __launch_bounds__(512) void gemm1(
    const float* __restrict__ mask,
    const unsigned short* __restrict__ vwf,
    float* __restrict__ out1,
    float* __restrict__ out0)
{
    __shared__ unsigned short As[2][32 * AP];   // 2 x 8.7 KB
    const int bx  = blockIdx.x;
    const int b   = bx & 7;                     // XCD swizzle: same-b -> same XCD
    const int tt  = (bx >> 3) & 7;
    const int kc  = bx >> 6;                    // 0..7, K-chunk 512
    const int t0  = tt * 32;
    const int k0  = kc * 512;
    const int tid = threadIdx.x;
    const int w    = tid >> 6;
    const int lane = tid & 63;
    const int quad = lane >> 4;
    const int l15  = lane & 15;

    const float* mbase = mask + (size_t)b * TGT * SRC + (size_t)t0 * SRC + k0;
    float*       obase = out1 + (size_t)b * TGT * SRC + (size_t)t0 * SRC + k0;
    const int sr0 = tid >> 5, sr1 = sr0 + 16, sc = (tid & 31) * 4;

    // wave w owns e' columns [w*32, w*32+32): et pair (2w, 2w+1)
    const unsigned short* bfr0 = vwf + (((size_t)b * 16 + 2 * w) * 128 + (size_t)kc * 16) * 512;
    const unsigned short* bfr1 = bfr0 + (size_t)128 * 512;

    // prologue: stage A(0)
    {
        f4 v0 = *(const f4*)(mbase + (size_t)sr0 * SRC + sc);
        f4 v1 = *(const f4*)(mbase + (size_t)sr1 * SRC + sc);
        *(f4*)(obase + (size_t)sr0 * SRC + sc) = v0;
        *(f4*)(obase + (size_t)sr1 * SRC + sc) = v1;
        u16x4 p0, p1;
        #pragma unroll
        for (int j = 0; j < 4; ++j) { p0[j] = f2b(v0[j]); p1[j] = f2b(v1[j]); }
        *(u16x4*)&As[0][sr0 * AP + sc] = p0;
        *(u16x4*)&As[0][sr1 * AP + sc] = p1;
    }
    __syncthreads();

    f32x4 acc00 = {}, acc01 = {}, acc10 = {}, acc11 = {};

    #pragma unroll
    for (int s = 0; s < 4; ++s) {               // 4 stages x 128 k
        f4 a0v, a1v;
        if (s < 3) {
            a0v = *(const f4*)(mbase + (size_t)sr0 * SRC + (s + 1) * 128 + sc);
            a1v = *(const f4*)(mbase + (size_t)sr1 * SRC + (s + 1) * 128 + sc);
        }
        #pragma unroll
        for (int q = 0; q < 4; ++q) {
            bf16x8 B0 = *(const bf16x8*)(bfr0 + ((size_t)(s * 4 + q) * 64 + lane) * 8);
            bf16x8 B1 = *(const bf16x8*)(bfr1 + ((size_t)(s * 4 + q) * 64 + lane) * 8);
            bf16x8 a0 = *(const bf16x8*)&As[s & 1][ l15       * AP + q * 32 + quad * 8];
            bf16x8 a1 = *(const bf16x8*)&As[s & 1][(l15 + 16) * AP + q * 32 + quad * 8];
            acc00 = __builtin_amdgcn_mfma_f32_16x16x32_bf16(a0, B0, acc00, 0, 0, 0);
            acc01 = __builtin_amdgcn_mfma_f32_16x16x32_bf16(a0, B1, acc01, 0, 0, 0);
            acc10 = __builtin_amdgcn_mfma_f32_16x16x32_bf16(a1, B0, acc10, 0, 0, 0);
            acc11 = __builtin_amdgcn_mfma_f32_16x16x32_bf16(a1, B1, acc11, 0, 0, 0);
        }
        if (s < 3) {
            *(f4*)(obase + (size_t)sr0 * SRC + (s + 1) * 128 + sc) = a0v;
            *(f4*)(obase + (size_t)sr1 * SRC + (s + 1) * 128 + sc) = a1v;
            u16x4 p0, p1;
            #pragma unroll
            for (int j = 0; j < 4; ++j) { p0[j] = f2b(a0v[j]); p1[j] = f2b(a1v[j]); }
            *(u16x4*)&As[(s + 1) & 1][sr0 * AP + sc] = p0;
            *(u16x4*)&As[(s + 1) & 1][sr1 * AP + sc] = p1;
        }
        __syncthreads();
    }

    // ---- epilogue: direct atomic accumulation into out0[t, b, e']
    // D layout: col = lane&15 (n), row = quad*4 + reg (m)  [verified m89/m91]
    {
        const int c0 = w * 32 + l15;
        #pragma unroll
        for (int r = 0; r < 4; ++r) {
            int tA = t0 + quad * 4 + r;
            int tB = tA + 16;
            float* oA = out0 + (size_t)tA * (BSZ * E) + (size_t)b * E;
            float* oB = out0 + (size_t)tB * (BSZ * E) + (size_t)b * E;
            atomicAdd(oA + c0,      acc00[r]);
            atomicAdd(oA + c0 + 16, acc01[r]);
            atomicAdd(oB + c0,      acc10[r]);
            atomicAdd(oB + c0 + 16, acc11[r]);
        }
    }
}

// ---------------------------------------------------------------------------
extern "C" void kernel_launch(void* const* d_in, const int* in_sizes, int n_in,
                              void* d_out, int out_size, void* d_ws, size_t ws_size,
                              hipStream_t stream)
{
    // inputs: 0=query(unused) 1=key(unused) 2=value 3=proposal_mask 4=W 5=bias
    const float* value = (const float*)d_in[2];
    const float* mask  = (const float*)d_in[3];
    const float* wgt   = (const float*)d_in[4];
    const float* bias  = (const float*)d_in[5];

    float* out0 = (float*)d_out;                              // (256,8,256)
    float* out1 = (float*)d_out + (size_t)TGT * BSZ * E;      // (8,256,4096)

    // ws layout: vwf bf16 16.8MB
    unsigned short* vwf = (unsigned short*)d_ws;

    prep_vw<<<dim3(64, 9), 256, 0, stream>>>(value, wgt, bias, vwf, out0);
    gemm1<<<512, 512, 0, stream>>>(mask, vwf, out1, out0);
}

// Round 3
// 179.077 us; speedup vs baseline: 1.1777x; 1.1777x over previous
//
#include <hip/hip_runtime.h>
#include <hip/hip_bf16.h>

#define TGT 256
#define BSZ 8
#define E   256
#define SRC 4096

typedef __attribute__((ext_vector_type(8))) short           bf16x8;
typedef __attribute__((ext_vector_type(4))) float           f32x4;
typedef __attribute__((ext_vector_type(4))) float           f4;
typedef __attribute__((ext_vector_type(8))) unsigned short  u16x8;
typedef __attribute__((ext_vector_type(4))) unsigned short  u16x4;

__device__ inline unsigned short f2b(float x) {
    union { __hip_bfloat16 h; unsigned short u; } cv;
    cv.h = __float2bfloat16(x);
    return cv.u;
}

__device__ inline bf16x8 cvt8v(const float* __restrict__ p) {
    f4 lo = *(const f4*)p;
    f4 hi = *(const f4*)(p + 4);
    bf16x8 r;
    #pragma unroll
    for (int j = 0; j < 4; ++j) { r[j] = (short)f2b(lo[j]); r[4 + j] = (short)f2b(hi[j]); }
    return r;
}

// ---------------------------------------------------------------------------
// prep_w: W(E,E) fp32 -> wf in B-fragment order (bf16), ONCE.
//   wf[((et*8 + ks)*64 + lane)*8 + j] = W[et*16+(lane&15)][ks*32+(lane>>4)*8+j]
// Separate launch so prep_vw can consume it (stream-ordered, no intra-kernel
// ordering hazard — the round-2 on-the-fly rebuild was the 70 µs regression).
// ---------------------------------------------------------------------------
__global__ __launch_bounds__(128) void prep_w(
    const float* __restrict__ wgt, unsigned short* __restrict__ wf)
{
    int o    = blockIdx.x * 128 + threadIdx.x;   // 0..8191
    int et   = o >> 9;
    int ks   = (o >> 6) & 7;
    int lane = o & 63;
    int quad = lane >> 4, l15 = lane & 15;
    bf16x8 v = cvt8v(wgt + (size_t)(et * 16 + l15) * E + ks * 32 + quad * 8);
    *(bf16x8*)&wf[(size_t)o * 8] = v;
}

// ---------------------------------------------------------------------------
// prep_vw: grid (64, 9).
//  by<8 : VW pass — VW[s,n] = sum_e V[s,b,e]*W[n,e] (bf16 MFMA, fp32 acc),
//         B-frags read from precomputed wf (coalesced, L2-resident 128 KB).
//         Result stored to vwf in gemm1's B-fragment order.
//  by==8: out0 init — out0[t,b,e] = bias[e] (gemm1 atomically accumulates;
//         runs every launch -> idempotent).
// ---------------------------------------------------------------------------
__global__ __launch_bounds__(256) void prep_vw(
    const float* __restrict__ value, const unsigned short* __restrict__ wf,
    const float* __restrict__ bias,
    unsigned short* __restrict__ vwf, float* __restrict__ out0)
{
    const int tid = threadIdx.x;

    if (blockIdx.y == 8) {               // ---- bias-init of out0 (2 MB)
        #pragma unroll
        for (int s = 0; s < 8; ++s) {
            int f4i = s * 16384 + blockIdx.x * 256 + tid;   // 0..131071
            *(f4*)(out0 + (size_t)f4i * 4) = *(const f4*)(bias + (f4i & 63) * 4);
        }
        return;
    }

    __shared__ unsigned short tile[64 * 264];   // pitch 264 u16
    const int sc64 = blockIdx.x;                // 0..63 (s-chunk)
    const int b    = blockIdx.y;
    const int s0   = sc64 * 64;

    // ---- stage V chunk (64 s-rows x 256 e) -> bf16 LDS
    #pragma unroll
    for (int i = 0; i < 16; ++i) {
        int lin = i * 256 + tid;                // 0..4095
        int row = lin >> 6;                     // s-local 0..63
        int c4  = lin & 63;                     // e float4 idx
        f4 v = *(const f4*)(value + (size_t)(s0 + row) * (BSZ * E)
                                  + (size_t)b * E + c4 * 4);
        u16x4 pk;
        #pragma unroll
        for (int j = 0; j < 4; ++j) pk[j] = f2b(v[j]);
        *(u16x4*)&tile[row * 264 + c4 * 4] = pk;
    }
    __syncthreads();

    const int w    = tid >> 6;                  // wave 0..3 owns s-rows [w*16, w*16+16)
    const int lane = tid & 63;
    const int quad = lane >> 4;
    const int l15  = lane & 15;

    // A-frags: m = s-local (w*16 + l15), k = e
    bf16x8 a[8];
    #pragma unroll
    for (int ks = 0; ks < 8; ++ks)
        a[ks] = *(const bf16x8*)&tile[(w * 16 + l15) * 264 + ks * 32 + quad * 8];

    // ---- VW = Vtile @ W^T ; B-frags stream from wf (coalesced 16B/lane)
    const unsigned short* bfw = wf + (size_t)lane * 8;
    #pragma unroll
    for (int et = 0; et < 16; ++et) {
        f32x4 acc = {};
        #pragma unroll
        for (int ks = 0; ks < 8; ++ks) {
            bf16x8 bb = *(const bf16x8*)(bfw + (size_t)(et * 8 + ks) * 512);
            acc = __builtin_amdgcn_mfma_f32_16x16x32_bf16(a[ks], bb, acc, 0, 0, 0);
        }
        // D layout: col = lane&15 (n-local), row = quad*4 + r (m-local)
        #pragma unroll
        for (int r = 0; r < 4; ++r)
            tile[(w * 16 + quad * 4 + r) * 264 + et * 16 + l15] = f2b(acc[r]);
    }
    __syncthreads();

    // ---- repack VW tile (rows = s-local, cols = n) into B-frag order
    #pragma unroll
    for (int i = 0; i < 8; ++i) {
        int o    = i * 256 + tid;               // 0..2047 octets
        int et   = o >> 7;
        int ksl  = (o >> 6) & 1;
        int ln   = o & 63;
        int q2   = ln >> 4, p15 = ln & 15;
        u16x8 pk;
        #pragma unroll
        for (int j = 0; j < 8; ++j)
            pk[j] = tile[(ksl * 32 + q2 * 8 + j) * 264 + et * 16 + p15];
        size_t ks = (size_t)sc64 * 2 + ksl;
        *(u16x8*)&vwf[((((size_t)b * 16 + et) * 128 + ks) * 64 + ln) * 8] = pk;
    }
}

// ---------------------------------------------------------------------------
// gemm1: per block (b, tt, kc): acc = M_b[32t, 512k] @ VW_b[512k, 256n],
// then atomicAdd into out0. Single-barrier design:
//   1. whole 32x512 mask tile -> regs -> bf16 LDS (one 33 KB buffer)
//   2. ONE __syncthreads (drains only mask loads + ds_writes)
//   3. out1 copy issued AFTER the barrier (stores drain under MFMA loop)
//   4. uninterrupted 16-step MFMA loop, B-frags streaming from L2/L3
// vs the old 4-stage loop with 4 barriers each draining out1 stores (vmcnt 0).
// Block = (b, tt, kc): 8*8*8 = 512 blocks (2/CU), 512 thr.
// ---------------------------------------------------------------------------
#define GP 520   // A pitch u16: 1040 B rows (16B-aligned)

__global__ __launch_bounds__(512, 4) void gemm1(
    const float* __restrict__ mask,
    const unsigned short* __restrict__ vwf,
    float* __restrict__ out1,
    float* __restrict__ out0)
{
    __shared__ unsigned short As[32 * GP];      // 33.3 KB
    const int bx  = blockIdx.x;
    const int b   = bx & 7;                     // XCD swizzle: same-b -> same XCD
    const int tt  = (bx >> 3) & 7;
    const int kc  = bx >> 6;                    // 0..7, K-chunk 512
    const int t0  = tt * 32;
    const int k0  = kc * 512;
    const int tid = threadIdx.x;
    const int w    = tid >> 6;
    const int lane = tid & 63;
    const int quad = lane >> 4;
    const int l15  = lane & 15;

    const float* mbase = mask + (size_t)b * TGT * SRC + (size_t)t0 * SRC + k0;
    float*       obase = out1 + (size_t)b * TGT * SRC + (size_t)t0 * SRC + k0;

    // ---- stage whole tile: thread -> row tid>>4 (0..31), f4-cols (tid&15)+j*16
    const int srow = tid >> 4;
    const int sc4  = tid & 15;
    f4 mv[8];
    #pragma unroll
    for (int j = 0; j < 8; ++j)
        mv[j] = *(const f4*)(mbase + (size_t)srow * SRC + (sc4 + j * 16) * 4);
    #pragma unroll
    for (int j = 0; j < 8; ++j) {
        u16x4 pk;
        #pragma unroll
        for (int t = 0; t < 4; ++t) pk[t] = f2b(mv[j][t]);
        *(u16x4*)&As[srow * GP + (sc4 + j * 16) * 4] = pk;
    }
    __syncthreads();

    // out1 copy after the barrier: these stores retire under the MFMA loop
    #pragma unroll
    for (int j = 0; j < 8; ++j)
        *(f4*)(obase + (size_t)srow * SRC + (sc4 + j * 16) * 4) = mv[j];

    // wave w owns e' columns [w*32, w*32+32): et pair (2w, 2w+1)
    const unsigned short* bfr0 = vwf + (((size_t)b * 16 + 2 * w) * 128 + (size_t)kc * 16) * 512;
    const unsigned short* bfr1 = bfr0 + (size_t)128 * 512;

    f32x4 acc00 = {}, acc01 = {}, acc10 = {}, acc11 = {};
    #pragma unroll 4
    for (int q = 0; q < 16; ++q) {
        bf16x8 B0 = *(const bf16x8*)(bfr0 + ((size_t)q * 64 + lane) * 8);
        bf16x8 B1 = *(const bf16x8*)(bfr1 + ((size_t)q * 64 + lane) * 8);
        bf16x8 a0 = *(const bf16x8*)&As[ l15       * GP + q * 32 + quad * 8];
        bf16x8 a1 = *(const bf16x8*)&As[(l15 + 16) * GP + q * 32 + quad * 8];
        acc00 = __builtin_amdgcn_mfma_f32_16x16x32_bf16(a0, B0, acc00, 0, 0, 0);
        acc01 = __builtin_amdgcn_mfma_f32_16x16x32_bf16(a0, B1, acc01, 0, 0, 0);
        acc10 = __builtin_amdgcn_mfma_f32_16x16x32_bf16(a1, B0, acc10, 0, 0, 0);
        acc11 = __builtin_amdgcn_mfma_f32_16x16x32_bf16(a1, B1, acc11, 0, 0, 0);
    }

    // ---- epilogue: direct atomic accumulation into out0[t, b, e']
    // D layout: col = lane&15 (n), row = quad*4 + reg (m)  [verified m89/m91]
    {
        const int c0 = w * 32 + l15;
        #pragma unroll
        for (int r = 0; r < 4; ++r) {
            int tA = t0 + quad * 4 + r;
            int tB = tA + 16;
            float* oA = out0 + (size_t)tA * (BSZ * E) + (size_t)b * E;
            float* oB = out0 + (size_t)tB * (BSZ * E) + (size_t)b * E;
            atomicAdd(oA + c0,      acc00[r]);
            atomicAdd(oA + c0 + 16, acc01[r]);
            atomicAdd(oB + c0,      acc10[r]);
            atomicAdd(oB + c0 + 16, acc11[r]);
        }
    }
}

// ---------------------------------------------------------------------------
extern "C" void kernel_launch(void* const* d_in, const int* in_sizes, int n_in,
                              void* d_out, int out_size, void* d_ws, size_t ws_size,
                              hipStream_t stream)
{
    // inputs: 0=query(unused) 1=key(unused) 2=value 3=proposal_mask 4=W 5=bias
    const float* value = (const float*)d_in[2];
    const float* mask  = (const float*)d_in[3];
    const float* wgt   = (const float*)d_in[4];
    const float* bias  = (const float*)d_in[5];

    float* out0 = (float*)d_out;                              // (256,8,256)
    float* out1 = (float*)d_out + (size_t)TGT * BSZ * E;      // (8,256,4096)

    // ws layout: vwf bf16 16.8MB | wf bf16 128KB
    unsigned short* vwf = (unsigned short*)d_ws;
    unsigned short* wf  = vwf + (size_t)BSZ * E * SRC;

    prep_w <<<64, 128, 0, stream>>>(wgt, wf);
    prep_vw<<<dim3(64, 9), 256, 0, stream>>>(value, wf, bias, vwf, out0);
    gemm1  <<<512, 512, 0, stream>>>(mask, vwf, out1, out0);
}

// Round 4
// 160.943 us; speedup vs baseline: 1.3104x; 1.1127x over previous
//
#include <hip/hip_runtime.h>
#include <hip/hip_bf16.h>

#define TGT 256
#define BSZ 8
#define E   256
#define SRC 4096

typedef __attribute__((ext_vector_type(8))) short           bf16x8;
typedef __attribute__((ext_vector_type(4))) float           f32x4;
typedef __attribute__((ext_vector_type(4))) float           f4;
typedef __attribute__((ext_vector_type(8))) unsigned short  u16x8;
typedef __attribute__((ext_vector_type(4))) unsigned short  u16x4;

__device__ inline unsigned short f2b(float x) {
    union { __hip_bfloat16 h; unsigned short u; } cv;
    cv.h = __float2bfloat16(x);
    return cv.u;
}

__device__ inline bf16x8 cvt8v(const float* __restrict__ p) {
    f4 lo = *(const f4*)p;
    f4 hi = *(const f4*)(p + 4);
    bf16x8 r;
    #pragma unroll
    for (int j = 0; j < 4; ++j) { r[j] = (short)f2b(lo[j]); r[4 + j] = (short)f2b(hi[j]); }
    return r;
}

// ---------------------------------------------------------------------------
// prep_w: W(E,E) fp32 -> wf in B-fragment order (bf16), ONCE.
//   wf[((et*8 + ks)*64 + lane)*8 + j] = W[et*16+(lane&15)][ks*32+(lane>>4)*8+j]
// ---------------------------------------------------------------------------
__global__ __launch_bounds__(128) void prep_w(
    const float* __restrict__ wgt, unsigned short* __restrict__ wf)
{
    int o    = blockIdx.x * 128 + threadIdx.x;   // 0..8191
    int et   = o >> 9;
    int ks   = (o >> 6) & 7;
    int lane = o & 63;
    int quad = lane >> 4, l15 = lane & 15;
    bf16x8 v = cvt8v(wgt + (size_t)(et * 16 + l15) * E + ks * 32 + quad * 8);
    *(bf16x8*)&wf[(size_t)o * 8] = v;
}

// ---------------------------------------------------------------------------
// prep_vw: grid (64, 9) x 512 thr.
//  by<8 : VW pass — VW[s,n] = sum_e V[s,b,e]*W[n,e] (bf16 MFMA, fp32 acc).
//    8 waves: wave w -> m-tile mt=w>>1 (16 s-rows), et half (w&1)*8..+8.
//    MFMA loop is ks-outer / et-inner: 8 independent wf loads batched, then
//    8 independent MFMAs -> latency-hiding ILP (round-3 version was a serial
//    load->mfma chain at 52 VGPRs, 20% occupancy, 50 us).
//    Result stored to vwf in gemm1's B-fragment order.
//  by==8: out0 init — out0[t,b,e] = bias[e] (gemm1 atomically accumulates).
// ---------------------------------------------------------------------------
__global__ __launch_bounds__(512, 4) void prep_vw(
    const float* __restrict__ value, const unsigned short* __restrict__ wf,
    const float* __restrict__ bias,
    unsigned short* __restrict__ vwf, float* __restrict__ out0)
{
    const int tid = threadIdx.x;

    if (blockIdx.y == 8) {               // ---- bias-init of out0 (2 MB)
        #pragma unroll
        for (int s = 0; s < 4; ++s) {
            int f4i = s * 32768 + blockIdx.x * 512 + tid;   // 0..131071
            *(f4*)(out0 + (size_t)f4i * 4) = *(const f4*)(bias + (f4i & 63) * 4);
        }
        return;
    }

    __shared__ unsigned short tile[64 * 264];   // pitch 264 u16
    const int sc64 = blockIdx.x;                // 0..63 (s-chunk)
    const int b    = blockIdx.y;
    const int s0   = sc64 * 64;

    // ---- stage V chunk (64 s-rows x 256 e) -> bf16 LDS
    #pragma unroll
    for (int i = 0; i < 8; ++i) {
        int lin = i * 512 + tid;                // 0..4095
        int row = lin >> 6;                     // s-local 0..63
        int c4  = lin & 63;                     // e float4 idx
        f4 v = *(const f4*)(value + (size_t)(s0 + row) * (BSZ * E)
                                  + (size_t)b * E + c4 * 4);
        u16x4 pk;
        #pragma unroll
        for (int j = 0; j < 4; ++j) pk[j] = f2b(v[j]);
        *(u16x4*)&tile[row * 264 + c4 * 4] = pk;
    }
    __syncthreads();

    const int w    = tid >> 6;                  // wave 0..7
    const int lane = tid & 63;
    const int quad = lane >> 4;
    const int l15  = lane & 15;
    const int mt   = w >> 1;                    // m-tile 0..3 (16 s-rows each)
    const int et0  = (w & 1) * 8;               // et half

    // A-frags into registers BEFORE any D write-back (cross-wave hazard:
    // the other half-wave of this m-tile writes D into these rows)
    bf16x8 a[8];
    #pragma unroll
    for (int ks = 0; ks < 8; ++ks)
        a[ks] = *(const bf16x8*)&tile[(mt * 16 + l15) * 264 + ks * 32 + quad * 8];
    __syncthreads();

    // ---- VW = Vtile @ W^T ; ks-outer: 8 batched loads + 8 indep MFMAs/step
    const unsigned short* bfw = wf + ((size_t)et0 * 8) * 512 + (size_t)lane * 8;
    f32x4 acc[8] = {};
    #pragma unroll
    for (int ks = 0; ks < 8; ++ks) {
        bf16x8 bb[8];
        #pragma unroll
        for (int e = 0; e < 8; ++e)
            bb[e] = *(const bf16x8*)(bfw + (size_t)(e * 8 + ks) * 512);
        #pragma unroll
        for (int e = 0; e < 8; ++e)
            acc[e] = __builtin_amdgcn_mfma_f32_16x16x32_bf16(a[ks], bb[e], acc[e], 0, 0, 0);
    }

    // D layout: col = lane&15 (n-local), row = quad*4 + r (m-local)
    #pragma unroll
    for (int e = 0; e < 8; ++e)
        #pragma unroll
        for (int r = 0; r < 4; ++r)
            tile[(mt * 16 + quad * 4 + r) * 264 + (et0 + e) * 16 + l15] = f2b(acc[e][r]);
    __syncthreads();

    // ---- repack VW tile (rows = s-local, cols = n) into B-frag order
    #pragma unroll
    for (int i = 0; i < 4; ++i) {
        int o    = i * 512 + tid;               // 0..2047 octets
        int et   = o >> 7;
        int ksl  = (o >> 6) & 1;
        int ln   = o & 63;
        int q2   = ln >> 4, p15 = ln & 15;
        u16x8 pk;
        #pragma unroll
        for (int j = 0; j < 8; ++j)
            pk[j] = tile[(ksl * 32 + q2 * 8 + j) * 264 + et * 16 + p15];
        size_t ks = (size_t)sc64 * 2 + ksl;
        *(u16x8*)&vwf[((((size_t)b * 16 + et) * 128 + ks) * 64 + ln) * 8] = pk;
    }
}

// ---------------------------------------------------------------------------
// gemm1: per block (b, tt, kc): acc = M_b[32t, 512k] @ VW_b[512k, 256n],
// then atomicAdd into out0. Single-barrier design (unchanged from round 3).
// ---------------------------------------------------------------------------
#define GP 520   // A pitch u16: 1040 B rows (16B-aligned)

__global__ __launch_bounds__(512, 4) void gemm1(
    const float* __restrict__ mask,
    const unsigned short* __restrict__ vwf,
    float* __restrict__ out1,
    float* __restrict__ out0)
{
    __shared__ unsigned short As[32 * GP];      // 33.3 KB
    const int bx  = blockIdx.x;
    const int b   = bx & 7;                     // XCD swizzle: same-b -> same XCD
    const int tt  = (bx >> 3) & 7;
    const int kc  = bx >> 6;                    // 0..7, K-chunk 512
    const int t0  = tt * 32;
    const int k0  = kc * 512;
    const int tid = threadIdx.x;
    const int w    = tid >> 6;
    const int lane = tid & 63;
    const int quad = lane >> 4;
    const int l15  = lane & 15;

    const float* mbase = mask + (size_t)b * TGT * SRC + (size_t)t0 * SRC + k0;
    float*       obase = out1 + (size_t)b * TGT * SRC + (size_t)t0 * SRC + k0;

    // ---- stage whole tile: thread -> row tid>>4 (0..31), f4-cols (tid&15)+j*16
    const int srow = tid >> 4;
    const int sc4  = tid & 15;
    f4 mv[8];
    #pragma unroll
    for (int j = 0; j < 8; ++j)
        mv[j] = *(const f4*)(mbase + (size_t)srow * SRC + (sc4 + j * 16) * 4);
    #pragma unroll
    for (int j = 0; j < 8; ++j) {
        u16x4 pk;
        #pragma unroll
        for (int t = 0; t < 4; ++t) pk[t] = f2b(mv[j][t]);
        *(u16x4*)&As[srow * GP + (sc4 + j * 16) * 4] = pk;
    }
    __syncthreads();

    // out1 copy after the barrier: these stores retire under the MFMA loop
    #pragma unroll
    for (int j = 0; j < 8; ++j)
        *(f4*)(obase + (size_t)srow * SRC + (sc4 + j * 16) * 4) = mv[j];

    // wave w owns e' columns [w*32, w*32+32): et pair (2w, 2w+1)
    const unsigned short* bfr0 = vwf + (((size_t)b * 16 + 2 * w) * 128 + (size_t)kc * 16) * 512;
    const unsigned short* bfr1 = bfr0 + (size_t)128 * 512;

    f32x4 acc00 = {}, acc01 = {}, acc10 = {}, acc11 = {};
    #pragma unroll 4
    for (int q = 0; q < 16; ++q) {
        bf16x8 B0 = *(const bf16x8*)(bfr0 + ((size_t)q * 64 + lane) * 8);
        bf16x8 B1 = *(const bf16x8*)(bfr1 + ((size_t)q * 64 + lane) * 8);
        bf16x8 a0 = *(const bf16x8*)&As[ l15       * GP + q * 32 + quad * 8];
        bf16x8 a1 = *(const bf16x8*)&As[(l15 + 16) * GP + q * 32 + quad * 8];
        acc00 = __builtin_amdgcn_mfma_f32_16x16x32_bf16(a0, B0, acc00, 0, 0, 0);
        acc01 = __builtin_amdgcn_mfma_f32_16x16x32_bf16(a0, B1, acc01, 0, 0, 0);
        acc10 = __builtin_amdgcn_mfma_f32_16x16x32_bf16(a1, B0, acc10, 0, 0, 0);
        acc11 = __builtin_amdgcn_mfma_f32_16x16x32_bf16(a1, B1, acc11, 0, 0, 0);
    }

    // ---- epilogue: direct atomic accumulation into out0[t, b, e']
    // D layout: col = lane&15 (n), row = quad*4 + reg (m)  [verified m89/m91]
    {
        const int c0 = w * 32 + l15;
        #pragma unroll
        for (int r = 0; r < 4; ++r) {
            int tA = t0 + quad * 4 + r;
            int tB = tA + 16;
            float* oA = out0 + (size_t)tA * (BSZ * E) + (size_t)b * E;
            float* oB = out0 + (size_t)tB * (BSZ * E) + (size_t)b * E;
            atomicAdd(oA + c0,      acc00[r]);
            atomicAdd(oA + c0 + 16, acc01[r]);
            atomicAdd(oB + c0,      acc10[r]);
            atomicAdd(oB + c0 + 16, acc11[r]);
        }
    }
}

// ---------------------------------------------------------------------------
extern "C" void kernel_launch(void* const* d_in, const int* in_sizes, int n_in,
                              void* d_out, int out_size, void* d_ws, size_t ws_size,
                              hipStream_t stream)
{
    // inputs: 0=query(unused) 1=key(unused) 2=value 3=proposal_mask 4=W 5=bias
    const float* value = (const float*)d_in[2];
    const float* mask  = (const float*)d_in[3];
    const float* wgt   = (const float*)d_in[4];
    const float* bias  = (const float*)d_in[5];

    float* out0 = (float*)d_out;                              // (256,8,256)
    float* out1 = (float*)d_out + (size_t)TGT * BSZ * E;      // (8,256,4096)

    // ws layout: vwf bf16 16.8MB | wf bf16 128KB
    unsigned short* vwf = (unsigned short*)d_ws;
    unsigned short* wf  = vwf + (size_t)BSZ * E * SRC;

    prep_w <<<64, 128, 0, stream>>>(wgt, wf);
    prep_vw<<<dim3(64, 9), 512, 0, stream>>>(value, wf, bias, vwf, out0);
    gemm1  <<<512, 512, 0, stream>>>(mask, vwf, out1, out0);
}